// Round 10
// baseline (259.163 us; speedup 1.0000x reference)
//
#include <hip/hip_runtime.h>
#include <hip/hip_fp8.h>

// CausalConv3dFP8 round 10: MX fp8 32x32x64. Batch-fused wave tile
// [b2][ct2][nf2] = 2 batches x 64co x 64w (acc 128 regs): A-reuse x4 -> 512 B/MFMA
// from L1, B 1024 B/MFMA from LDS — both supply pipes ~50-60% busy at MFMA peak.
// Split-half conflict-free LDS, kd-outer staging, kd-skip, XCD h-band swizzle.
// xq layout: [b][d4][hp194][ci32 grp 4][wp322][32B]
// wpk layout: [tap27][cc2][cq4][lane64][32B]

using f32x16 = __attribute__((ext_vector_type(16))) float;
using i32x8 = __attribute__((ext_vector_type(8))) int;
using i32x4 = __attribute__((ext_vector_type(4))) int;
typedef long long i64;
struct alignas(16) L2v { i64 x, y; };

namespace {
constexpr int Cc = 128, Dd = 4, Hh = 192, Ww = 320;
constexpr int HP = 194, WP = 322;
constexpr int NTAP = 27;
constexpr size_t PLANE = (size_t)4 * WP * 32;               // 41,216 B per (b,d,h) row-plane
constexpr size_t XQ_BYTES = (size_t)2 * Dd * HP * PLANE;    // 63,967,232
constexpr int ZA = 8 * 2 * 2576;
constexpr int ZB = 8 * 192 * 32;
constexpr int GSTR = WP * 32;                               // 10,304 B per ci32-group
constexpr int HB = 1056;                                    // 66*16: half-plane stride in LDS
constexpr int BSTR = 4 * 4 * 2 * HB;                        // 33,792: per-batch LDS block
}

__global__ __launch_bounds__(256) void zero_pad_kernel(unsigned char* __restrict__ xq) {
  int i = blockIdx.x * 256 + threadIdx.x;
  if (i < ZA) {
    int bd = i / (2 * 2576);
    int r = i - bd * (2 * 2576);
    int hsel = r / 2576, seg = r - hsel * 2576;
    L2v z{0, 0};
    *(L2v*)(xq + ((size_t)bd * HP + (hsel ? 193 : 0)) * PLANE + (size_t)seg * 16) = z;
  } else if (i < ZA + ZB) {
    int j = i - ZA;
    int bd = j / (192 * 32);
    int r = j - bd * (192 * 32);
    int h = r / 32 + 1;
    int t = r & 31;
    int g = t >> 3, s2 = t & 7;
    int wsel = s2 >> 2, part = s2 & 3;
    *(i64*)(xq + ((size_t)bd * HP + h) * PLANE + (size_t)g * GSTR
            + (size_t)(wsel ? 321 : 0) * 32 + part * 8) = 0;
  }
}

__global__ __launch_bounds__(256) void qx_kernel(const float* __restrict__ x,
                                                 unsigned char* __restrict__ xq) {
  __shared__ unsigned char lt[64 * 136];
  const int tid = threadIdx.x;
  const int b = blockIdx.z >> 2, d = blockIdx.z & 3;
  const int h = blockIdx.y;
  const int w0 = blockIdx.x * 64;
  const int wl = tid & 63, cig = tid >> 6;
  const size_t cstr = (size_t)Dd * Hh * Ww;
  const float* xp = x + (((size_t)b * Cc * Dd + d) * Hh + h) * Ww + w0 + wl;
  #pragma unroll 4
  for (int i = 0; i < 32; ++i) {
    int ci = cig * 32 + i;
    __hip_fp8_e4m3 q(xp[ci * cstr]);
    lt[wl * 136 + ci] = q.__x;
  }
  __syncthreads();
  unsigned char* plane = xq + ((size_t)(b * Dd + d) * HP + h + 1) * PLANE;
  {
    int g = tid >> 6, w = tid & 63;
    const unsigned char* src = lt + w * 136 + g * 32;
    i64 a0 = *(const i64*)(src), a1 = *(const i64*)(src + 8);
    i64 a2 = *(const i64*)(src + 16), a3 = *(const i64*)(src + 24);
    unsigned char* dst = plane + (size_t)g * GSTR + (size_t)(w0 + 1 + w) * 32;
    *(L2v*)dst = L2v{a0, a1};
    *(L2v*)(dst + 16) = L2v{a2, a3};
  }
}

__global__ void wpack_kernel(const float* __restrict__ w, unsigned char* __restrict__ wpk) {
  int idx = blockIdx.x * 256 + threadIdx.x;
  if (idx >= Cc * Cc * NTAP) return;
  int tap = idx % NTAP;
  int t = idx / NTAP;
  int ci = t % Cc, co = t / Cc;
  int cc = ci >> 6, cq = co >> 5;
  int lane = (((ci >> 5) & 1) << 5) | (co & 31);
  __hip_fp8_e4m3 q(w[idx]);
  wpk[((((size_t)tap * 2 + cc) * 4 + cq) * 64 + lane) * 32 + (ci & 31)] = q.__x;
}

__global__ __launch_bounds__(256, 2) void conv_mfma(const unsigned char* __restrict__ xq,
                                                    const unsigned char* __restrict__ wpk,
                                                    float* __restrict__ out) {
  __shared__ unsigned char lb[2 * BSTR];           // [bsel2][hrow4][g4][half2][66w][16B] = 67,584
  const int tid = threadIdx.x;
  const int lane = tid & 63, wv = tid >> 6;
  const int l31 = lane & 31, chalf = lane >> 5;
  const int hr = wv >> 1, ch = wv & 1;             // wave: h-row, cout-half (64 co)
  // ---- bijective XCD h-band swizzle (both batches in-block now) ----
  const int id = blockIdx.x;
  const int xcd = id & 7, j = id >> 3;
  const int h0l = j / 20, rem = j - h0l * 20;
  const int wx = rem >> 2, dout = rem & 3;
  const int h0 = (xcd * 12 + h0l) * 2;
  const int w0 = wx * 64;
  const int kdmin = dout >= 2 ? 0 : 2 - dout;

  const unsigned char* bb[3];
  #pragma unroll
  for (int kw = 0; kw < 3; ++kw)
    bb[kw] = lb + (hr * 4 + chalf) * 2 * HB + (l31 + kw) * 16;

  f32x16 acc[2][2][2];                             // [bsel][ct][nf]
  #pragma unroll
  for (int s = 0; s < 2; ++s)
    #pragma unroll
    for (int a = 0; a < 2; ++a)
      #pragma unroll
      for (int n = 0; n < 2; ++n)
        #pragma unroll
        for (int r = 0; r < 16; ++r) acc[s][a][n][r] = 0.f;

  for (int kd = kdmin; kd < 3; ++kd) {
    __syncthreads();
    // ---- stage both batches for this kd: 2112 x 32B units, split-half ----
    for (int u = tid; u < 2112; u += 256) {
      int w = u % 66, rest = u / 66;
      int bsel = rest >> 4, r = rest & 15;
      int g = r & 3, hrow = r >> 2;
      const unsigned char* src = xq
          + ((size_t)(bsel * Dd + dout + kd - 2) * HP + h0 + hrow) * PLANE
          + (size_t)g * GSTR + (size_t)(w0 + w) * 32;
      L2v lo = *(const L2v*)src;
      L2v hi = *(const L2v*)(src + 16);
      unsigned char* base = lb + bsel * BSTR + (hrow * 4 + g) * 2 * HB + w * 16;
      *(L2v*)(base) = lo;
      *(L2v*)(base + HB) = hi;
    }
    __syncthreads();
    __builtin_amdgcn_s_setprio(1);
    #pragma unroll
    for (int kh = 0; kh < 3; ++kh)
      #pragma unroll
      for (int cc = 0; cc < 2; ++cc)
        #pragma unroll
        for (int kw = 0; kw < 3; ++kw) {
          // ---- A: 2 ct x 32B, direct vector load (reused over bsel x nf = 4) ----
          i32x8 av[2];
          #pragma unroll
          for (int ct = 0; ct < 2; ++ct)
            av[ct] = *(const i32x8*)(wpk +
                ((((size_t)((kd * 9 + kh * 3 + kw) * 2) + cc) * 4 + ch * 2 + ct) * 64 + lane) * 32);
          #pragma unroll
          for (int bsel = 0; bsel < 2; ++bsel)
            #pragma unroll
            for (int nf = 0; nf < 2; ++nf) {
              const int off = bsel * BSTR + (kh * 4 + cc * 2) * 2 * HB + nf * 512;
              i32x4 blo = *(const i32x4*)(bb[kw] + off);
              i32x4 bhi = *(const i32x4*)(bb[kw] + off + HB);
              i32x8 bv = __builtin_shufflevector(blo, bhi, 0, 1, 2, 3, 4, 5, 6, 7);
              #pragma unroll
              for (int ct = 0; ct < 2; ++ct)
                acc[bsel][ct][nf] = __builtin_amdgcn_mfma_scale_f32_32x32x64_f8f6f4(
                    av[ct], bv, acc[bsel][ct][nf], 0, 0, 0, 127, 0, 127);
            }
        }
    __builtin_amdgcn_s_setprio(0);
  }

  // ---- epilogue: col=l31 -> w, row=(reg&3)+8*(reg>>2)+4*chalf -> cout ----
  #pragma unroll
  for (int bsel = 0; bsel < 2; ++bsel)
    #pragma unroll
    for (int ct = 0; ct < 2; ++ct)
      #pragma unroll
      for (int nf = 0; nf < 2; ++nf) {
        int ww = w0 + nf * 32 + l31;
        #pragma unroll
        for (int reg = 0; reg < 16; ++reg) {
          int co = ch * 64 + ct * 32 + (reg & 3) + 8 * (reg >> 2) + 4 * chalf;
          out[(((size_t)bsel * Cc + co) * Dd + dout) * (size_t)(Hh * Ww)
              + (size_t)(h0 + hr) * Ww + ww] = acc[bsel][ct][nf][reg];
        }
      }
}

extern "C" void kernel_launch(void* const* d_in, const int* in_sizes, int n_in,
                              void* d_out, int out_size, void* d_ws, size_t ws_size,
                              hipStream_t stream) {
  const float* x = (const float*)d_in[0];
  const float* w = (const float*)d_in[1];
  unsigned char* xq = (unsigned char*)d_ws;
  unsigned char* wpk = xq + XQ_BYTES;              // 442,368 B
  float* out = (float*)d_out;

  int nz = ZA + ZB;
  zero_pad_kernel<<<(nz + 255) / 256, 256, 0, stream>>>(xq);

  dim3 g1(Ww / 64, Hh, 2 * Dd);
  qx_kernel<<<g1, 256, 0, stream>>>(x, xq);

  int nw = Cc * Cc * NTAP;
  wpack_kernel<<<(nw + 255) / 256, 256, 0, stream>>>(w, wpk);

  conv_mfma<<<dim3(1920), 256, 0, stream>>>(xq, wpk, out);
}

// Round 11
// 228.771 us; speedup vs baseline: 1.1328x; 1.1328x over previous
//
#include <hip/hip_runtime.h>
#include <hip/hip_fp8.h>

// CausalConv3dFP8 round 11: r9 tile + LDS double-buffer staged by global_load_lds
// with counted vmcnt(9) (T3/T4-minimum): stage kd+1 under compute of kd.
// 9 uniform gll per thread per phase (8x16B + 1x4B tail) so vmcnt immediates are exact.
// Split-half conflict-free LDS, kd-skip, bijective XCD h-band swizzle.
// xq layout: [b][d4][hp194][ci32 grp 4][wp322][32B]
// wpk layout: [tap27][cc2][cq4][lane64][32B]

using f32x16 = __attribute__((ext_vector_type(16))) float;
using i32x8 = __attribute__((ext_vector_type(8))) int;
using i32x4 = __attribute__((ext_vector_type(4))) int;
typedef long long i64;
struct alignas(16) L2v { i64 x, y; };

namespace {
constexpr int Cc = 128, Dd = 4, Hh = 192, Ww = 320;
constexpr int HP = 194, WP = 322;
constexpr int NTAP = 27;
constexpr size_t PLANE = (size_t)4 * WP * 32;               // 41,216 B per (b,d,h) row-plane
constexpr size_t XQ_BYTES = (size_t)2 * Dd * HP * PLANE;    // 63,967,232
constexpr int ZA = 8 * 2 * 2576;
constexpr int ZB = 8 * 192 * 32;
constexpr int GSTR = WP * 32;                               // 10,304 B per ci32-group
constexpr int HB = 1056;                                    // 66*16: half-plane stride in LDS
constexpr int BUFB = 2112 * 16;                             // 33,792 B per LDS buffer
}

__global__ __launch_bounds__(256) void zero_pad_kernel(unsigned char* __restrict__ xq) {
  int i = blockIdx.x * 256 + threadIdx.x;
  if (i < ZA) {
    int bd = i / (2 * 2576);
    int r = i - bd * (2 * 2576);
    int hsel = r / 2576, seg = r - hsel * 2576;
    L2v z{0, 0};
    *(L2v*)(xq + ((size_t)bd * HP + (hsel ? 193 : 0)) * PLANE + (size_t)seg * 16) = z;
  } else if (i < ZA + ZB) {
    int j = i - ZA;
    int bd = j / (192 * 32);
    int r = j - bd * (192 * 32);
    int h = r / 32 + 1;
    int t = r & 31;
    int g = t >> 3, s2 = t & 7;
    int wsel = s2 >> 2, part = s2 & 3;
    *(i64*)(xq + ((size_t)bd * HP + h) * PLANE + (size_t)g * GSTR
            + (size_t)(wsel ? 321 : 0) * 32 + part * 8) = 0;
  }
}

__global__ __launch_bounds__(256) void qx_kernel(const float* __restrict__ x,
                                                 unsigned char* __restrict__ xq) {
  __shared__ unsigned char lt[64 * 136];
  const int tid = threadIdx.x;
  const int b = blockIdx.z >> 2, d = blockIdx.z & 3;
  const int h = blockIdx.y;
  const int w0 = blockIdx.x * 64;
  const int wl = tid & 63, cig = tid >> 6;
  const size_t cstr = (size_t)Dd * Hh * Ww;
  const float* xp = x + (((size_t)b * Cc * Dd + d) * Hh + h) * Ww + w0 + wl;
  #pragma unroll 4
  for (int i = 0; i < 32; ++i) {
    int ci = cig * 32 + i;
    __hip_fp8_e4m3 q(xp[ci * cstr]);
    lt[wl * 136 + ci] = q.__x;
  }
  __syncthreads();
  unsigned char* plane = xq + ((size_t)(b * Dd + d) * HP + h + 1) * PLANE;
  {
    int g = tid >> 6, w = tid & 63;
    const unsigned char* src = lt + w * 136 + g * 32;
    i64 a0 = *(const i64*)(src), a1 = *(const i64*)(src + 8);
    i64 a2 = *(const i64*)(src + 16), a3 = *(const i64*)(src + 24);
    unsigned char* dst = plane + (size_t)g * GSTR + (size_t)(w0 + 1 + w) * 32;
    *(L2v*)dst = L2v{a0, a1};
    *(L2v*)(dst + 16) = L2v{a2, a3};
  }
}

__global__ void wpack_kernel(const float* __restrict__ w, unsigned char* __restrict__ wpk) {
  int idx = blockIdx.x * 256 + threadIdx.x;
  if (idx >= Cc * Cc * NTAP) return;
  int tap = idx % NTAP;
  int t = idx / NTAP;
  int ci = t % Cc, co = t / Cc;
  int cc = ci >> 6, cq = co >> 5;
  int lane = (((ci >> 5) & 1) << 5) | (co & 31);
  __hip_fp8_e4m3 q(w[idx]);
  wpk[((((size_t)tap * 2 + cc) * 4 + cq) * 64 + lane) * 32 + (ci & 31)] = q.__x;
}

__device__ __forceinline__ void gll16(const unsigned char* g, unsigned char* l) {
  __builtin_amdgcn_global_load_lds(
      (const __attribute__((address_space(1))) void*)g,
      (__attribute__((address_space(3))) void*)l, 16, 0, 0);
}
__device__ __forceinline__ void gll4(const unsigned char* g, unsigned char* l) {
  __builtin_amdgcn_global_load_lds(
      (const __attribute__((address_space(1))) void*)g,
      (__attribute__((address_space(3))) void*)l, 4, 0, 0);
}

__global__ __launch_bounds__(256, 4) void conv_mfma(const unsigned char* __restrict__ xq,
                                                    const unsigned char* __restrict__ wpk,
                                                    float* __restrict__ out) {
  __shared__ unsigned char lb[2 * BUFB];           // dbuf x [hrow4][g4][half2][66w][16B]
  const int tid = threadIdx.x;
  const int lane = tid & 63, wv = tid >> 6;
  const int l31 = lane & 31, chalf = lane >> 5;
  const int hr = wv >> 1, ch = wv & 1;             // wave: h-row, cout-half (64 co)
  // ---- bijective XCD h-band swizzle ----
  const int id = blockIdx.x;
  const int xcd = id & 7, j = id >> 3;
  const int h0l = j / 40, rem = j - h0l * 40;
  const int z = rem / 5, wx = rem - z * 5;
  const int b = z >> 2, dout = z & 3;
  const int h0 = (xcd * 12 + h0l) * 2;
  const int w0 = wx * 64;
  const int kdmin = dout >= 2 ? 0 : 2 - dout;

  // ---- per-thread staging descriptors (kd-invariant; kd selects the d-image) ----
  size_t off16[8];
  int lds16[8];
  #pragma unroll
  for (int it = 0; it < 8; ++it) {
    int u = it * 256 + tid;                        // 16B unit 0..2047
    int rh = u / 66, w = u - rh * 66;
    int half = rh & 1, rg = rh >> 1;
    int g = rg & 3, hrow = rg >> 2;
    off16[it] = (size_t)(h0 + hrow) * PLANE + (size_t)g * GSTR
                + (size_t)(w0 + w) * 32 + half * 16;
    lds16[it] = u * 16;
  }
  size_t off4;
  int lds4 = 32768 + tid * 4;
  {
    int q = 2048 + (tid >> 2);                     // tail units 2048..2111, dword lanes
    int rh = q / 66, w = q - rh * 66;
    int half = rh & 1, rg = rh >> 1;
    int g = rg & 3, hrow = rg >> 2;
    off4 = (size_t)(h0 + hrow) * PLANE + (size_t)g * GSTR
           + (size_t)(w0 + w) * 32 + half * 16 + (tid & 3) * 4;
  }
  const size_t img0 = (size_t)(b * Dd + dout - 2) * HP * PLANE;  // + kd*HP*PLANE
  const size_t imgstep = (size_t)HP * PLANE;

  f32x16 acc[2][2];                                // [ct][nf]
  #pragma unroll
  for (int a = 0; a < 2; ++a)
    #pragma unroll
    for (int n = 0; n < 2; ++n)
      #pragma unroll
      for (int r = 0; r < 16; ++r) acc[a][n][r] = 0.f;

  // ---- prologue: stage first kd into buf 0 ----
  {
    const unsigned char* img = xq + img0 + (size_t)kdmin * imgstep;
    #pragma unroll
    for (int it = 0; it < 8; ++it) gll16(img + off16[it], lb + lds16[it]);
    gll4(img + off4, lb + lds4);
  }

  int p = 0;
  for (int kd = kdmin; kd < 3; ++kd) {
    // ---- issue next kd's stage into the other buffer (flies across barrier) ----
    if (kd + 1 < 3) {
      const unsigned char* img = xq + img0 + (size_t)(kd + 1) * imgstep;
      unsigned char* bufn = lb + (p ? 0 : BUFB);
      #pragma unroll
      for (int it = 0; it < 8; ++it) gll16(img + off16[it], bufn + lds16[it]);
      gll4(img + off4, bufn + lds4);
      asm volatile("s_waitcnt vmcnt(9)" ::: "memory");   // drain current's 9, keep next's 9
    } else {
      asm volatile("s_waitcnt vmcnt(0)" ::: "memory");
    }
    __builtin_amdgcn_s_barrier();
    __builtin_amdgcn_sched_barrier(0);

    const unsigned char* bufp = lb + (p ? BUFB : 0);
    const unsigned char* bb[3];
    #pragma unroll
    for (int kw = 0; kw < 3; ++kw)
      bb[kw] = bufp + (hr * 4 + chalf) * 2 * HB + (l31 + kw) * 16;

    __builtin_amdgcn_s_setprio(1);
    #pragma unroll
    for (int kh = 0; kh < 3; ++kh)
      #pragma unroll
      for (int cc = 0; cc < 2; ++cc)
        #pragma unroll
        for (int kw = 0; kw < 3; ++kw) {
          i32x8 av[2];
          #pragma unroll
          for (int ct = 0; ct < 2; ++ct)
            av[ct] = *(const i32x8*)(wpk +
                ((((size_t)((kd * 9 + kh * 3 + kw) * 2) + cc) * 4 + ch * 2 + ct) * 64 + lane) * 32);
          #pragma unroll
          for (int nf = 0; nf < 2; ++nf) {
            const int off = (kh * 4 + cc * 2) * 2 * HB + nf * 512;
            i32x4 blo = *(const i32x4*)(bb[kw] + off);
            i32x4 bhi = *(const i32x4*)(bb[kw] + off + HB);
            i32x8 bv = __builtin_shufflevector(blo, bhi, 0, 1, 2, 3, 4, 5, 6, 7);
            #pragma unroll
            for (int ct = 0; ct < 2; ++ct)
              acc[ct][nf] = __builtin_amdgcn_mfma_scale_f32_32x32x64_f8f6f4(
                  av[ct], bv, acc[ct][nf], 0, 0, 0, 127, 0, 127);
          }
        }
    __builtin_amdgcn_s_setprio(0);
    __builtin_amdgcn_s_barrier();                  // buf p free for next-next stage
    p ^= 1;
  }

  // ---- epilogue: col=l31 -> w, row=(reg&3)+8*(reg>>2)+4*chalf -> cout ----
  #pragma unroll
  for (int ct = 0; ct < 2; ++ct)
    #pragma unroll
    for (int nf = 0; nf < 2; ++nf) {
      int ww = w0 + nf * 32 + l31;
      #pragma unroll
      for (int reg = 0; reg < 16; ++reg) {
        int co = ch * 64 + ct * 32 + (reg & 3) + 8 * (reg >> 2) + 4 * chalf;
        out[(((size_t)b * Cc + co) * Dd + dout) * (size_t)(Hh * Ww)
            + (size_t)(h0 + hr) * Ww + ww] = acc[ct][nf][reg];
      }
    }
}

extern "C" void kernel_launch(void* const* d_in, const int* in_sizes, int n_in,
                              void* d_out, int out_size, void* d_ws, size_t ws_size,
                              hipStream_t stream) {
  const float* x = (const float*)d_in[0];
  const float* w = (const float*)d_in[1];
  unsigned char* xq = (unsigned char*)d_ws;
  unsigned char* wpk = xq + XQ_BYTES;              // 442,368 B
  float* out = (float*)d_out;

  int nz = ZA + ZB;
  zero_pad_kernel<<<(nz + 255) / 256, 256, 0, stream>>>(xq);

  dim3 g1(Ww / 64, Hh, 2 * Dd);
  qx_kernel<<<g1, 256, 0, stream>>>(x, xq);

  int nw = Cc * Cc * NTAP;
  wpack_kernel<<<(nw + 255) / 256, 256, 0, stream>>>(w, wpk);

  conv_mfma<<<dim3(3840), 256, 0, stream>>>(xq, wpk, out);
}